// Round 4
// baseline (96.149 us; speedup 1.0000x reference)
//
#include <hip/hip_runtime.h>

// DPLoss fused single-kernel, v4 — block-flat balanced decomposition.
// 256 blocks x 1024 threads; block b owns rows [16b, 16b+16).
// LDS prefix-sum of per-row float4-group counts; all threads flat-iterate the
// block's total groups, each element weighted by cached 1/L of its row
// (sum_elems d^2/L == sum_rows per_sample_mse). Block-wide reduce -> one
// atomicAdd(d_out)/block. d_out zeroed via captured memset node.

#define ROWS_PER_BLOCK 16

__global__ __launch_bounds__(1024) void dploss_fused_kernel(
    const float* __restrict__ pred,
    const float* __restrict__ align,
    const int* __restrict__ lens,
    float* __restrict__ out,
    int B, int T)
{
    __shared__ int   l_len[ROWS_PER_BLOCK];
    __shared__ float l_inv[ROWS_PER_BLOCK];
    __shared__ int   l_pre[ROWS_PER_BLOCK + 1];   // prefix of group counts
    __shared__ float wsum[16];

    const int row0 = blockIdx.x * ROWS_PER_BLOCK;
    const int tid  = threadIdx.x;

    if (tid < ROWS_PER_BLOCK) {
        const int row = row0 + tid;
        int L = (row < B) ? lens[row] : 0;
        l_len[tid] = L;
        l_inv[tid] = (L > 0) ? (1.0f / (float)L) : 0.0f;
    }
    __syncthreads();
    if (tid == 0) {
        int run = 0;
        #pragma unroll
        for (int r = 0; r < ROWS_PER_BLOCK; ++r) {
            l_pre[r] = run;
            run += (l_len[r] + 3) >> 2;
        }
        l_pre[ROWS_PER_BLOCK] = run;
    }
    __syncthreads();

    const int total = l_pre[ROWS_PER_BLOCK];
    float acc = 0.0f;

    for (int gf = tid; gf < total; gf += 1024) {
        // find row: linear scan over 16 prefix entries (LDS broadcast-hot)
        int r = 0;
        #pragma unroll
        for (int k = 1; k < ROWS_PER_BLOCK; ++k)
            r += (gf >= l_pre[k]) ? 1 : 0;

        const int   g    = gf - l_pre[r];
        const int   L    = l_len[r];
        const float invL = l_inv[r];
        const size_t off = (size_t)(row0 + r) * T;
        const float4 p = ((const float4*)(pred  + off))[g];
        const float4 a = ((const float4*)(align + off))[g];
        const int base = g << 2;

        float s;
        if (base + 4 <= L) {                       // fully valid group
            float d0 = p.x - __logf(a.x);
            float d1 = p.y - __logf(a.y);
            float d2 = p.z - __logf(a.z);
            float d3 = p.w - __logf(a.w);
            s = d0 * d0 + d1 * d1 + d2 * d2 + d3 * d3;
        } else {                                   // tail group
            s = 0.0f;
            if (base + 0 < L) { float d = p.x - __logf(a.x); s += d * d; }
            if (base + 1 < L) { float d = p.y - __logf(a.y); s += d * d; }
            if (base + 2 < L) { float d = p.z - __logf(a.z); s += d * d; }
        }
        acc += s * invL;
    }

    // wave-64 shuffle reduction
    #pragma unroll
    for (int o = 32; o > 0; o >>= 1)
        acc += __shfl_down(acc, o, 64);

    const int lane = tid & 63;
    const int wave = tid >> 6;
    if (lane == 0) wsum[wave] = acc;
    __syncthreads();

    if (tid == 0) {
        float t = 0.0f;
        #pragma unroll
        for (int w = 0; w < 16; ++w) t += wsum[w];
        atomicAdd(out, t / (float)B);
    }
}

extern "C" void kernel_launch(void* const* d_in, const int* in_sizes, int n_in,
                              void* d_out, int out_size, void* d_ws, size_t ws_size,
                              hipStream_t stream)
{
    const float* pred  = (const float*)d_in[0];
    const float* align = (const float*)d_in[1];
    const int*   lens  = (const int*)d_in[2];

    const int B = in_sizes[2];
    const int T = in_sizes[0] / B;

    float* out = (float*)d_out;

    hipMemsetAsync(out, 0, sizeof(float), stream);   // captured memset node

    const int grid = (B + ROWS_PER_BLOCK - 1) / ROWS_PER_BLOCK;
    dploss_fused_kernel<<<grid, 1024, 0, stream>>>(pred, align, lens, out, B, T);
}

// Round 5
// 94.959 us; speedup vs baseline: 1.0125x; 1.0125x over previous
//
#include <hip/hip_runtime.h>

// DPLoss fused single-kernel, v3 (reverted from v4 — balanced decomposition
// regressed: row-search VALU overhead > imbalance savings).
// - 1024-thread blocks (16 waves) -> 1 block/CU at B=4096, 256 atomics total.
// - One wave per row; branch-free main loop over fully-valid float4 groups;
//   <=3-element tail handled by the first lanes with scalar loads.
// - Per-wave shuffle reduce -> per-block LDS reduce -> one atomicAdd per block.
// - d_out zeroed via a captured hipMemsetAsync node.

__global__ __launch_bounds__(1024) void dploss_fused_kernel(
    const float* __restrict__ pred,
    const float* __restrict__ align,
    const int* __restrict__ lens,
    float* __restrict__ out,
    int B, int T)
{
    const int gtid = blockIdx.x * blockDim.x + threadIdx.x;
    const int wave = gtid >> 6;           // global wave id == row
    const int lane = threadIdx.x & 63;
    const int wave_in_block = threadIdx.x >> 6;

    float row_mse = 0.0f;

    if (wave < B) {
        const int row = wave;
        const int L = lens[row];          // wave-uniform -> scalar load
        const float* __restrict__ prow = pred  + (size_t)row * T;
        const float* __restrict__ arow = align + (size_t)row * T;
        const float4* __restrict__ p4 = (const float4*)prow;
        const float4* __restrict__ a4 = (const float4*)arow;
        const int nfull = L >> 2;         // fully-valid float4 groups

        float acc = 0.0f;
        #pragma unroll 2
        for (int g = lane; g < nfull; g += 64) {
            float4 p = p4[g];
            float4 a = a4[g];
            float d0 = p.x - __logf(a.x);
            float d1 = p.y - __logf(a.y);
            float d2 = p.z - __logf(a.z);
            float d3 = p.w - __logf(a.w);
            acc += d0 * d0 + d1 * d1 + d2 * d2 + d3 * d3;
        }

        // tail: L & 3 leftover elements, one per lane
        const int rem = L & 3;
        if (lane < rem) {
            const int idx = (nfull << 2) + lane;
            float d = prow[idx] - __logf(arow[idx]);
            acc += d * d;
        }

        // wave-64 shuffle reduction
        #pragma unroll
        for (int off = 32; off > 0; off >>= 1)
            acc += __shfl_down(acc, off, 64);

        row_mse = acc / (float)L;         // only lane 0's value matters
    }

    __shared__ float wsum[16];
    if (lane == 0) wsum[wave_in_block] = row_mse;
    __syncthreads();

    if (threadIdx.x == 0) {
        float total = 0.0f;
        #pragma unroll
        for (int w = 0; w < 16; ++w) total += wsum[w];
        atomicAdd(out, total / (float)B);
    }
}

extern "C" void kernel_launch(void* const* d_in, const int* in_sizes, int n_in,
                              void* d_out, int out_size, void* d_ws, size_t ws_size,
                              hipStream_t stream)
{
    const float* pred  = (const float*)d_in[0];
    const float* align = (const float*)d_in[1];
    const int*   lens  = (const int*)d_in[2];

    const int B = in_sizes[2];
    const int T = in_sizes[0] / B;

    float* out = (float*)d_out;

    // zero the scalar accumulator (captured as a memset node)
    hipMemsetAsync(out, 0, sizeof(float), stream);

    const int threads = 1024;                      // 16 waves per block
    const int waves_per_block = threads / 64;
    const int grid = (B + waves_per_block - 1) / waves_per_block;

    dploss_fused_kernel<<<grid, threads, 0, stream>>>(pred, align, lens, out, B, T);
}